// Round 1
// baseline (2411.355 us; speedup 1.0000x reference)
//
#include <hip/hip_runtime.h>
#include <math.h>

// ---------------------------------------------------------------------------
// Sender model, MI355X fp32 implementation.
// prev_hidden and hm = prev_hidden @ rec_kernel are loop-invariant (reference
// always feeds prev_hidden as the GRU state) -> computed once.
// Per step: GRU pointwise (+ x@k), logits GEMM fused with online softmax
// stats, finalize (merge halves, outputs, emb gather).
// ---------------------------------------------------------------------------

// ---------------- generic GEMM with bias: C[M,N] = A[M,K]@B[K,N] + bias -----
__global__ __launch_bounds__(256) void gemm_bias_kernel(
    const float* __restrict__ A, const float* __restrict__ Bm,
    const float* __restrict__ bias, float* __restrict__ C,
    int M, int N, int K, float* __restrict__ ml)
{
    __shared__ float As[16][68];   // As[k][m]
    __shared__ float Bs[16][68];   // Bs[k][n]
    const int tid = threadIdx.x;
    const int tx = tid & 15, ty = tid >> 4;
    const int m0 = blockIdx.y * 64, n0 = blockIdx.x * 64;
    const int arow = tid >> 2;          // 0..63
    const int akq  = (tid & 3) << 2;    // 0,4,8,12
    const int bkr  = tid >> 4;          // 0..15
    const int bnq  = (tid & 15) << 2;   // 0..60
    float acc[4][4] = {};
    for (int k0 = 0; k0 < K; k0 += 16) {
        float4 va = *(const float4*)&A[(size_t)(m0 + arow) * K + k0 + akq];
        float4 vb = *(const float4*)&Bm[(size_t)(k0 + bkr) * N + n0 + bnq];
        As[akq+0][arow] = va.x; As[akq+1][arow] = va.y;
        As[akq+2][arow] = va.z; As[akq+3][arow] = va.w;
        *(float4*)&Bs[bkr][bnq] = vb;
        __syncthreads();
        #pragma unroll
        for (int k = 0; k < 16; ++k) {
            float4 a = *(float4*)&As[k][ty << 2];
            float4 b = *(float4*)&Bs[k][tx << 2];
            float av[4] = {a.x, a.y, a.z, a.w};
            float bv[4] = {b.x, b.y, b.z, b.w};
            #pragma unroll
            for (int i = 0; i < 4; ++i)
                #pragma unroll
                for (int j = 0; j < 4; ++j)
                    acc[i][j] = fmaf(av[i], bv[j], acc[i][j]);
        }
        __syncthreads();
    }
    float4 bb = *(const float4*)&bias[n0 + (tx << 2)];
    float bvv[4] = {bb.x, bb.y, bb.z, bb.w};
    #pragma unroll
    for (int i = 0; i < 4; ++i) {
        float4 o = make_float4(acc[i][0] + bvv[0], acc[i][1] + bvv[1],
                               acc[i][2] + bvv[2], acc[i][3] + bvv[3]);
        *(float4*)&C[(size_t)(m0 + (ty << 2) + i) * N + n0 + (tx << 2)] = o;
    }
    // message_length output (all 6.0f), written by the N-tile-0 blocks
    if (ml != nullptr && blockIdx.x == 0 && tid < 64) ml[m0 + tid] = 6.0f;
}

// ---------------- GRU pointwise (+ x @ gru_kernel), 8 rows per block --------
__global__ __launch_bounds__(256) void gru_kernel(
    const float* __restrict__ x, const float* __restrict__ gk,
    const float* __restrict__ b_in, const float* __restrict__ hm,
    const float* __restrict__ ph, float* __restrict__ h,
    float* __restrict__ ht_out, int has_x)
{
    __shared__ float xsT[64][8];   // xsT[e][r]
    const int tid = threadIdx.x;   // j = output unit 0..255
    const int row0 = blockIdx.x * 8;
    float az[8], ar[8], ah[8];
    const float bz = b_in[tid], br = b_in[256 + tid], bh = b_in[512 + tid];
    #pragma unroll
    for (int r = 0; r < 8; ++r) { az[r] = bz; ar[r] = br; ah[r] = bh; }
    if (has_x) {
        for (int l = tid; l < 512; l += 256) {
            int r = l >> 6, e = l & 63;
            xsT[e][r] = x[(size_t)row0 * 64 + l];   // x[(row0+r)*64+e]
        }
        __syncthreads();
        #pragma unroll 4
        for (int e = 0; e < 64; ++e) {
            float kz  = gk[e * 768 + tid];
            float kr_ = gk[e * 768 + 256 + tid];
            float kh  = gk[e * 768 + 512 + tid];
            float4 x0 = *(float4*)&xsT[e][0];
            float4 x1 = *(float4*)&xsT[e][4];
            float xv[8] = {x0.x, x0.y, x0.z, x0.w, x1.x, x1.y, x1.z, x1.w};
            #pragma unroll
            for (int r = 0; r < 8; ++r) {
                az[r] = fmaf(xv[r], kz, az[r]);
                ar[r] = fmaf(xv[r], kr_, ar[r]);
                ah[r] = fmaf(xv[r], kh, ah[r]);
            }
        }
    }
    #pragma unroll
    for (int r = 0; r < 8; ++r) {
        const int row = row0 + r;
        float hz  = hm[(size_t)row * 768 + tid];
        float hr  = hm[(size_t)row * 768 + 256 + tid];
        float hh  = hm[(size_t)row * 768 + 512 + tid];
        float phv = ph[(size_t)row * 256 + tid];
        float z  = 1.0f / (1.0f + expf(-(az[r] + hz)));
        float rr = 1.0f / (1.0f + expf(-(ar[r] + hr)));
        float ht = tanhf(ah[r] + rr * hh);
        float hv = z * phv + (1.0f - z) * ht;
        h[(size_t)row * 256 + tid] = hv;
        if (ht_out) ht_out[(size_t)row * 256 + tid] = hv;
    }
}

// ---------------- logits GEMM fused with online softmax statistics ----------
// grid = 512: blockIdx.x -> (rowtile = bx>>1 [32 rows], half = bx&1 [2048 V])
// 256 threads: tx = tid&31 (v = v0 + tx*4), ty = tid>>5 (rows = ty*4 .. +3)
__global__ __launch_bounds__(256) void logits_kernel(
    const float* __restrict__ h, const float* __restrict__ Wo,
    const float* __restrict__ bo, float4* __restrict__ pstats)
{
    __shared__ float hs[256][32];    // h^T tile: hs[k][r]  (conflict-free)
    __shared__ float Bs[16][132];    // Wo tile:  Bs[k][v]
    const int tid = threadIdx.x;
    const int rowtile = blockIdx.x >> 1;
    const int half = blockIdx.x & 1;
    const int row0 = rowtile * 32;
    const int vbase = half * 2048;
    const int tx = tid & 31, ty = tid >> 5;

    // stage h^T (float4 per-row reads, consecutive-bank LDS writes)
    #pragma unroll
    for (int i = 0; i < 8; ++i) {
        int l = tid + (i << 8);          // 0..2047
        int r = l & 31;
        int kq = (l >> 5) << 2;          // 0..252
        float4 v = *(const float4*)&h[(size_t)(row0 + r) * 256 + kq];
        hs[kq+0][r] = v.x; hs[kq+1][r] = v.y; hs[kq+2][r] = v.z; hs[kq+3][r] = v.w;
    }

    float m[4] = {-INFINITY, -INFINITY, -INFINITY, -INFINITY};
    float s[4] = {0.f, 0.f, 0.f, 0.f};
    float q[4] = {0.f, 0.f, 0.f, 0.f};
    int  am[4] = {0, 0, 0, 0};

    for (int c = 0; c < 16; ++c) {       // 16 V-chunks of 128
        const int v0 = vbase + (c << 7);
        float acc[4][4] = {};
        for (int kt = 0; kt < 16; ++kt) {
            __syncthreads();             // protects Bs reuse (and hs on first pass)
            #pragma unroll
            for (int i = 0; i < 2; ++i) {
                int l = tid + (i << 8);  // 0..511
                int kr = l >> 5;         // 0..15
                int vq = (l & 31) << 2;  // 0..124
                *(float4*)&Bs[kr][vq] =
                    *(const float4*)&Wo[(size_t)((kt << 4) + kr) * 4096 + v0 + vq];
            }
            __syncthreads();
            #pragma unroll
            for (int k = 0; k < 16; ++k) {
                float4 b4 = *(float4*)&Bs[k][tx << 2];
                float4 a4 = *(float4*)&hs[(kt << 4) + k][ty << 2];
                float av[4] = {a4.x, a4.y, a4.z, a4.w};
                float bv[4] = {b4.x, b4.y, b4.z, b4.w};
                #pragma unroll
                for (int r = 0; r < 4; ++r)
                    #pragma unroll
                    for (int j = 0; j < 4; ++j)
                        acc[r][j] = fmaf(av[r], bv[j], acc[r][j]);
            }
        }
        // online update with this chunk's 16 logits
        float4 bov = *(const float4*)&bo[v0 + (tx << 2)];
        float bvv[4] = {bov.x, bov.y, bov.z, bov.w};
        #pragma unroll
        for (int r = 0; r < 4; ++r) {
            #pragma unroll
            for (int j = 0; j < 4; ++j) {
                float l = acc[r][j] + bvv[j];
                if (l > m[r]) {          // strict > keeps first max (v ascending per thread)
                    float f = expf(m[r] - l);   // exp(-inf)=0 on first value
                    s[r] = fmaf(s[r], f, 1.0f);
                    q[r] = fmaf(q[r], f, l);
                    m[r] = l;
                    am[r] = v0 + (tx << 2) + j;
                } else {
                    float e = expf(l - m[r]);
                    s[r] += e;
                    q[r] = fmaf(l, e, q[r]);
                }
            }
        }
    }
    // butterfly merge across the 32 tx-lanes (same ty = contiguous 32 lanes)
    #pragma unroll
    for (int off = 1; off < 32; off <<= 1) {
        #pragma unroll
        for (int r = 0; r < 4; ++r) {
            float m2 = __shfl_xor(m[r], off);
            float s2 = __shfl_xor(s[r], off);
            float q2 = __shfl_xor(q[r], off);
            int   a2 = __shfl_xor(am[r], off);
            float M  = fmaxf(m[r], m2);
            float f1 = expf(m[r] - M);
            float f2 = expf(m2 - M);
            s[r] = s[r] * f1 + s2 * f2;
            q[r] = q[r] * f1 + q2 * f2;
            am[r] = (m[r] > m2) ? am[r] : ((m2 > m[r]) ? a2 : (am[r] < a2 ? am[r] : a2));
            m[r] = M;
        }
    }
    if (tx == 0) {
        #pragma unroll
        for (int r = 0; r < 4; ++r) {
            int row = row0 + (ty << 2) + r;
            pstats[half * 8192 + row] = make_float4(m[r], s[r], q[r], __int_as_float(am[r]));
        }
    }
}

// ---------------- finalize: merge halves, outputs, emb gather ---------------
__global__ __launch_bounds__(256) void finalize_kernel(
    const float4* __restrict__ pstats, const float* __restrict__ emb,
    float* __restrict__ x, float* __restrict__ out_seq, float* __restrict__ out_sel,
    float* __restrict__ entacc, float* __restrict__ out_ent, int t, int last)
{
    __shared__ int syms[64];
    const int tid = threadIdx.x;
    const int b0 = blockIdx.x * 64;
    if (tid < 64) {
        int row = b0 + tid;
        float4 p0 = pstats[row];
        float4 p1 = pstats[8192 + row];
        float m0 = p0.x, s0 = p0.y, q0 = p0.z; int a0 = __float_as_int(p0.w);
        float m1 = p1.x, s1 = p1.y, q1 = p1.z; int a1 = __float_as_int(p1.w);
        float M  = fmaxf(m0, m1);
        float f0 = expf(m0 - M), f1 = expf(m1 - M);
        float S = s0 * f0 + s1 * f1;
        float Q = q0 * f0 + q1 * f1;
        int A = (m0 > m1) ? a0 : ((m1 > m0) ? a1 : (a0 < a1 ? a0 : a1));
        float lse = M + logf(S);
        float sel = M - lse;             // lp at argmax
        float ent = lse - Q / S;         // -sum(lp * exp(lp))
        out_seq[(size_t)row * 6 + t] = (float)A;
        out_sel[(size_t)row * 6 + t] = sel;
        float ea = (t == 0) ? ent : (entacc[row] + ent);
        if (last) out_ent[row] = ea * (1.0f / 6.0f);
        else entacc[row] = ea;
        syms[tid] = A;
    }
    __syncthreads();
    // gather next input: x[row] = emb[sym[row]]
    for (int l = tid; l < 4096; l += 256) {
        int r = l >> 6, e = l & 63;
        x[(size_t)(b0 + r) * 64 + e] = emb[(size_t)syms[r] * 64 + e];
    }
}

// ---------------------------------------------------------------------------
extern "C" void kernel_launch(void* const* d_in, const int* in_sizes, int n_in,
                              void* d_out, int out_size, void* d_ws, size_t ws_size,
                              hipStream_t stream) {
    const float* vis  = (const float*)d_in[0];   // (8192, 512)
    const float* Wv   = (const float*)d_in[1];   // (512, 256)
    const float* bv   = (const float*)d_in[2];   // (256,)
    const float* gk   = (const float*)d_in[3];   // (64, 768)
    const float* grk  = (const float*)d_in[4];   // (256, 768)
    const float* bin  = (const float*)d_in[5];   // (768,)
    const float* brec = (const float*)d_in[6];   // (768,)
    const float* Wo   = (const float*)d_in[7];   // (256, 4096)
    const float* bo   = (const float*)d_in[8];   // (4096,)
    const float* emb  = (const float*)d_in[9];   // (4096, 64)

    float* out = (float*)d_out;
    float* out_seq = out;                 // (8192, 6)
    float* out_sel = out + 49152;         // (8192, 6)
    float* out_ent = out + 98304;         // (8192,)
    float* out_ml  = out + 106496;        // (8192,)
    float* out_ht  = out + 114688;        // (8192, 256)

    char* ws = (char*)d_ws;
    float*  ph     = (float*)(ws);                     // 8192x256
    float*  hm     = (float*)(ws + 8388608);           // 8192x768
    float*  hbuf   = (float*)(ws + 33554432);          // 8192x256
    float*  xbuf   = (float*)(ws + 41943040);          // 8192x64
    float4* pstats = (float4*)(ws + 44040192);         // 2x8192 float4
    float*  entacc = (float*)(ws + 44302336);          // 8192

    // K1: prev_hidden = vis @ Wv + bv   (also writes message_length)
    dim3 g1(256 / 64, 8192 / 64);
    gemm_bias_kernel<<<g1, 256, 0, stream>>>(vis, Wv, bv, ph, 8192, 256, 512, out_ml);
    // K2: hm = prev_hidden @ grk + brec   (loop-invariant)
    dim3 g2(768 / 64, 8192 / 64);
    gemm_bias_kernel<<<g2, 256, 0, stream>>>(ph, grk, brec, hm, 8192, 768, 256, nullptr);

    for (int t = 0; t < 6; ++t) {
        gru_kernel<<<1024, 256, 0, stream>>>(xbuf, gk, bin, hm, ph, hbuf,
                                             (t == 5) ? out_ht : nullptr,
                                             (t > 0) ? 1 : 0);
        logits_kernel<<<512, 256, 0, stream>>>(hbuf, Wo, bo, pstats);
        finalize_kernel<<<128, 256, 0, stream>>>(pstats, emb, xbuf, out_seq, out_sel,
                                                 entacc, out_ent, t, (t == 5) ? 1 : 0);
    }
}

// Round 2
// 1675.976 us; speedup vs baseline: 1.4388x; 1.4388x over previous
//
#include <hip/hip_runtime.h>
#include <math.h>

// ---------------------------------------------------------------------------
// Sender model, MI355X fp32 implementation, round 2.
// prev_hidden and hm = prev_hidden @ rec_kernel are loop-invariant -> once.
// Per step: GRU pointwise (+ emb-gather + x@k), logits GEMM fused with online
// softmax stats (64x256 block tile, 8x8 reg tile), finalize (merge 16 tiles).
// ---------------------------------------------------------------------------

// XOR swizzle spreading stride-8-float b128 reads over all 8 bank quads
__device__ __forceinline__ int swz(int v) { return v ^ ((v >> 6) << 2); }

// One block computes a 64x256 tile of A[M,K]@B[K,N] (+bias).
// STATS: emit online-softmax partials per (row, n-tile); else store C.
// 256 threads: tx = tid&31 -> cols n0+8*tx..+7, ty = tid>>5 -> rows m0+8*ty..+7
template<int KTOT, bool STATS>
__global__ __launch_bounds__(256, 4) void gemm64x256(
    const float* __restrict__ A, const float* __restrict__ Bm,
    const float* __restrict__ bias, float* __restrict__ C,
    int ldb, int ldc, float4* __restrict__ pstats)
{
    __shared__ float As[32][64];    // 8 KB, As[k][m] (reads broadcast per 32-lane group)
    __shared__ float Bs[32][256];   // 32 KB, swizzled cols       -> 40960 B total
    const int tid = threadIdx.x;
    const int tx = tid & 31, ty = tid >> 5;
    const int n0 = blockIdx.x << 8;
    const int m0 = blockIdx.y << 6;

    const int sv0 = swz(tx << 3);
    const int sv1 = swz((tx << 3) + 4);
    float acc[8][8] = {};

    for (int k0 = 0; k0 < KTOT; k0 += 32) {
        __syncthreads();
        #pragma unroll
        for (int i = 0; i < 2; ++i) {           // stage A: 64 rows x 32 k
            int l = tid + (i << 8);             // 0..511
            int r = l >> 3, kq = (l & 7) << 2;
            float4 a = *(const float4*)&A[(size_t)(m0 + r) * KTOT + k0 + kq];
            As[kq + 0][r] = a.x; As[kq + 1][r] = a.y;
            As[kq + 2][r] = a.z; As[kq + 3][r] = a.w;
        }
        #pragma unroll
        for (int i = 0; i < 8; ++i) {           // stage B: 32 k x 256 n
            int l = tid + (i << 8);             // 0..2047
            int k = l >> 6, vq = (l & 63) << 2;
            *(float4*)&Bs[k][swz(vq)] =
                *(const float4*)&Bm[(size_t)(k0 + k) * ldb + n0 + vq];
        }
        __syncthreads();
        #pragma unroll
        for (int k = 0; k < 32; ++k) {
            float4 a0 = *(float4*)&As[k][ty << 3];
            float4 a1 = *(float4*)&As[k][(ty << 3) + 4];
            float4 b0 = *(float4*)&Bs[k][sv0];
            float4 b1 = *(float4*)&Bs[k][sv1];
            float av[8] = {a0.x,a0.y,a0.z,a0.w,a1.x,a1.y,a1.z,a1.w};
            float bv[8] = {b0.x,b0.y,b0.z,b0.w,b1.x,b1.y,b1.z,b1.w};
            #pragma unroll
            for (int i2 = 0; i2 < 8; ++i2)
                #pragma unroll
                for (int j = 0; j < 8; ++j)
                    acc[i2][j] = fmaf(av[i2], bv[j], acc[i2][j]);
        }
    }

    float4 bb0 = *(const float4*)&bias[n0 + (tx << 3)];
    float4 bb1 = *(const float4*)&bias[n0 + (tx << 3) + 4];
    float bv[8] = {bb0.x,bb0.y,bb0.z,bb0.w,bb1.x,bb1.y,bb1.z,bb1.w};

    if (STATS) {
        #pragma unroll
        for (int i = 0; i < 8; ++i) {
            // per-thread online pass over 8 cols (v ascending, strict > keeps first max)
            float m = -INFINITY, s = 0.f, q = 0.f; int am = 0;
            #pragma unroll
            for (int j = 0; j < 8; ++j) {
                float l = acc[i][j] + bv[j];
                if (l > m) {
                    float f = expf(m - l);      // exp(-inf)=0 on first value
                    s = fmaf(s, f, 1.0f);
                    q = fmaf(q, f, l);
                    m = l; am = n0 + (tx << 3) + j;
                } else {
                    float e = expf(l - m);
                    s += e; q = fmaf(l, e, q);
                }
            }
            // butterfly merge across the 32 tx lanes (contiguous 32-lane group)
            #pragma unroll
            for (int off = 1; off < 32; off <<= 1) {
                float m2 = __shfl_xor(m, off);
                float s2 = __shfl_xor(s, off);
                float q2 = __shfl_xor(q, off);
                int   a2 = __shfl_xor(am, off);
                float M = fmaxf(m, m2);
                float f1 = expf(m - M), f2 = expf(m2 - M);
                s = s * f1 + s2 * f2;
                q = q * f1 + q2 * f2;
                am = (m > m2) ? am : ((m2 > m) ? a2 : (am < a2 ? am : a2));
                m = M;
            }
            if (tx == 0)
                pstats[(blockIdx.x << 13) + m0 + (ty << 3) + i] =
                    make_float4(m, s, q, __int_as_float(am));
        }
    } else {
        #pragma unroll
        for (int i = 0; i < 8; ++i) {
            float4 o0 = make_float4(acc[i][0]+bv[0], acc[i][1]+bv[1],
                                    acc[i][2]+bv[2], acc[i][3]+bv[3]);
            float4 o1 = make_float4(acc[i][4]+bv[4], acc[i][5]+bv[5],
                                    acc[i][6]+bv[6], acc[i][7]+bv[7]);
            size_t base = (size_t)(m0 + (ty << 3) + i) * ldc + n0 + (tx << 3);
            *(float4*)&C[base]     = o0;
            *(float4*)&C[base + 4] = o1;
        }
    }
}

// ---------------- GRU pointwise (+ emb gather + x @ gru_kernel) -------------
__global__ __launch_bounds__(256) void gru_kernel(
    const int* __restrict__ syms, const float* __restrict__ emb,
    const float* __restrict__ gk, const float* __restrict__ b_in,
    const float* __restrict__ hm, const float* __restrict__ ph,
    float* __restrict__ h, float* __restrict__ ht_out, int has_x)
{
    __shared__ float xsT[64][8];   // xsT[e][r]
    const int tid = threadIdx.x;   // output unit 0..255
    const int row0 = blockIdx.x * 8;
    float az[8], ar[8], ah[8];
    const float bz = b_in[tid], br = b_in[256 + tid], bh = b_in[512 + tid];
    #pragma unroll
    for (int r = 0; r < 8; ++r) { az[r] = bz; ar[r] = br; ah[r] = bh; }
    if (has_x) {
        for (int l = tid; l < 512; l += 256) {
            int r = l >> 6, e = l & 63;
            xsT[e][r] = emb[(size_t)syms[row0 + r] * 64 + e];
        }
        __syncthreads();
        #pragma unroll 4
        for (int e = 0; e < 64; ++e) {
            float kz  = gk[e * 768 + tid];
            float kr_ = gk[e * 768 + 256 + tid];
            float kh  = gk[e * 768 + 512 + tid];
            float4 x0 = *(float4*)&xsT[e][0];
            float4 x1 = *(float4*)&xsT[e][4];
            float xv[8] = {x0.x, x0.y, x0.z, x0.w, x1.x, x1.y, x1.z, x1.w};
            #pragma unroll
            for (int r = 0; r < 8; ++r) {
                az[r] = fmaf(xv[r], kz, az[r]);
                ar[r] = fmaf(xv[r], kr_, ar[r]);
                ah[r] = fmaf(xv[r], kh, ah[r]);
            }
        }
    }
    #pragma unroll
    for (int r = 0; r < 8; ++r) {
        const int row = row0 + r;
        float hz  = hm[(size_t)row * 768 + tid];
        float hr  = hm[(size_t)row * 768 + 256 + tid];
        float hh  = hm[(size_t)row * 768 + 512 + tid];
        float phv = ph[(size_t)row * 256 + tid];
        float z  = 1.0f / (1.0f + expf(-(az[r] + hz)));
        float rr = 1.0f / (1.0f + expf(-(ar[r] + hr)));
        float ht = tanhf(ah[r] + rr * hh);
        float hv = z * phv + (1.0f - z) * ht;
        h[(size_t)row * 256 + tid] = hv;
        if (ht_out) ht_out[(size_t)row * 256 + tid] = hv;
    }
}

// ---------------- finalize: merge 16 n-tile partials, outputs ---------------
__global__ __launch_bounds__(64) void finalize_kernel(
    const float4* __restrict__ pstats, int* __restrict__ syms,
    float* __restrict__ out_seq, float* __restrict__ out_sel,
    float* __restrict__ out_ent, float* __restrict__ out_ml, int t, int last)
{
    const int row = blockIdx.x * 64 + threadIdx.x;
    float M = -INFINITY, S = 0.f, Q = 0.f; int A = 0;
    #pragma unroll
    for (int p = 0; p < 16; ++p) {              // v ascending: ties keep lower A
        float4 pp = pstats[(p << 13) + row];
        float m2 = pp.x, s2 = pp.y, q2 = pp.z; int a2 = __float_as_int(pp.w);
        if (m2 > M) {
            float f = expf(M - m2);             // exp(-inf)=0 on first tile
            S = S * f + s2; Q = Q * f + q2; M = m2; A = a2;
        } else {
            float f = expf(m2 - M);
            S = fmaf(s2, f, S); Q = fmaf(q2, f, Q);
        }
    }
    float lse = M + logf(S);
    float sel = M - lse;                        // lp at argmax
    float ent = lse - Q / S;                    // -sum(lp * exp(lp))
    out_seq[(size_t)row * 6 + t] = (float)A;
    out_sel[(size_t)row * 6 + t] = sel;
    float ea = (t == 0) ? ent : (out_ent[row] + ent);
    out_ent[row] = last ? ea * (1.0f / 6.0f) : ea;
    if (t == 0) out_ml[row] = 6.0f;
    syms[row] = A;
}

// ---------------------------------------------------------------------------
extern "C" void kernel_launch(void* const* d_in, const int* in_sizes, int n_in,
                              void* d_out, int out_size, void* d_ws, size_t ws_size,
                              hipStream_t stream) {
    const float* vis  = (const float*)d_in[0];   // (8192, 512)
    const float* Wv   = (const float*)d_in[1];   // (512, 256)
    const float* bv   = (const float*)d_in[2];   // (256,)
    const float* gk   = (const float*)d_in[3];   // (64, 768)
    const float* grk  = (const float*)d_in[4];   // (256, 768)
    const float* bin  = (const float*)d_in[5];   // (768,)
    const float* brec = (const float*)d_in[6];   // (768,)
    const float* Wo   = (const float*)d_in[7];   // (256, 4096)
    const float* bo   = (const float*)d_in[8];   // (4096,)
    const float* emb  = (const float*)d_in[9];   // (4096, 64)

    float* out = (float*)d_out;
    float* out_seq = out;                 // (8192, 6)
    float* out_sel = out + 49152;         // (8192, 6)
    float* out_ent = out + 98304;         // (8192,)
    float* out_ml  = out + 106496;        // (8192,)
    float* out_ht  = out + 114688;        // (8192, 256)

    char* ws = (char*)d_ws;
    float*  ph     = (float*)(ws);                     // 8192x256   (8 MB)
    float*  hm     = (float*)(ws + 8388608);           // 8192x768   (24 MB)
    float*  hbuf   = (float*)(ws + 33554432);          // 8192x256   (8 MB)
    float4* pstats = (float4*)(ws + 41943040);         // 16x8192    (2 MB)
    int*    syms   = (int*)(ws + 44040192);            // 8192       (32 KB)

    // K1: prev_hidden = vis @ Wv + bv
    gemm64x256<512, false><<<dim3(1, 128), 256, 0, stream>>>(
        vis, Wv, bv, ph, 256, 256, nullptr);
    // K2: hm = prev_hidden @ grk + brec   (loop-invariant)
    gemm64x256<256, false><<<dim3(3, 128), 256, 0, stream>>>(
        ph, grk, brec, hm, 768, 768, nullptr);

    for (int t = 0; t < 6; ++t) {
        gru_kernel<<<1024, 256, 0, stream>>>(syms, emb, gk, bin, hm, ph, hbuf,
                                             (t == 5) ? out_ht : nullptr,
                                             (t > 0) ? 1 : 0);
        gemm64x256<256, true><<<dim3(16, 128), 256, 0, stream>>>(
            hbuf, Wo, bo, nullptr, 4096, 0, pstats);
        finalize_kernel<<<128, 64, 0, stream>>>(pstats, syms, out_seq, out_sel,
                                                out_ent, out_ml, t, (t == 5) ? 1 : 0);
    }
}

// Round 3
// 1263.900 us; speedup vs baseline: 1.9079x; 1.3260x over previous
//
#include <hip/hip_runtime.h>
#include <math.h>

// ---------------------------------------------------------------------------
// Sender model, MI355X, round 3: logits GEMM on bf16 MFMA via exact-enough
// fp32 emulation (x = b0+b1+b2 bf16 splits, 6 products >= 2^-16 weight,
// fp32 MFMA accumulate -> error ~2^-27 rel, argmax-safe).
// Wo transposed+split once (loop-invariant); h split fused into GRU kernel.
// ---------------------------------------------------------------------------

typedef __attribute__((ext_vector_type(8))) short short8v;   // 8 bf16 = 4 VGPR
typedef __attribute__((ext_vector_type(4))) float f32x4;

__device__ __forceinline__ unsigned short bf16_rtne(float v, float& back) {
    unsigned int u = __float_as_uint(v);
    unsigned int r = (u + 0x7FFFu + ((u >> 16) & 1u)) >> 16;
    back = __uint_as_float(r << 16);
    return (unsigned short)r;
}

// ---------------- one-time: WoT[c][n][k] bf16 splits of Wo[k][n] ------------
__global__ __launch_bounds__(256) void prep_wot(
    const float* __restrict__ Wo, unsigned short* __restrict__ w0,
    unsigned short* __restrict__ w1, unsigned short* __restrict__ w2)
{
    __shared__ float Ts[64][65];
    const int tid = threadIdx.x;
    const int n0 = blockIdx.x * 64, k0 = blockIdx.y * 64;
    const int ty = tid >> 2, tx = tid & 3;
    #pragma unroll
    for (int q = 0; q < 4; ++q) {
        float4 v = *(const float4*)&Wo[(size_t)(k0 + ty) * 4096 + n0 + tx * 16 + q * 4];
        Ts[ty][tx * 16 + q * 4 + 0] = v.x; Ts[ty][tx * 16 + q * 4 + 1] = v.y;
        Ts[ty][tx * 16 + q * 4 + 2] = v.z; Ts[ty][tx * 16 + q * 4 + 3] = v.w;
    }
    __syncthreads();
    #pragma unroll
    for (int ii = 0; ii < 2; ++ii) {
        int item = tid + (ii << 8);          // 0..511
        int n = item >> 3, g = item & 7;     // n 0..63, k-group 0..7
        unsigned int p0[4], p1[4], p2[4];
        #pragma unroll
        for (int e2 = 0; e2 < 4; ++e2) {
            unsigned int a0, a1, a2, b0, b1, b2;
            {
                float v = Ts[g * 8 + e2 * 2][n], bk;
                a0 = bf16_rtne(v, bk); float r1 = v - bk;
                a1 = bf16_rtne(r1, bk); float r2 = r1 - bk;
                float d; a2 = bf16_rtne(r2, d);
            }
            {
                float v = Ts[g * 8 + e2 * 2 + 1][n], bk;
                b0 = bf16_rtne(v, bk); float r1 = v - bk;
                b1 = bf16_rtne(r1, bk); float r2 = r1 - bk;
                float d; b2 = bf16_rtne(r2, d);
            }
            p0[e2] = a0 | (b0 << 16); p1[e2] = a1 | (b1 << 16); p2[e2] = a2 | (b2 << 16);
        }
        size_t base = (size_t)(n0 + n) * 256 + k0 + g * 8;
        *(uint4*)&w0[base] = make_uint4(p0[0], p0[1], p0[2], p0[3]);
        *(uint4*)&w1[base] = make_uint4(p1[0], p1[1], p1[2], p1[3]);
        *(uint4*)&w2[base] = make_uint4(p2[0], p2[1], p2[2], p2[3]);
    }
}

// ---------------- fp32 GEMM (K1/K2 only): C[M,N]=A@B+bias ------------------
__device__ __forceinline__ int swz(int v) { return v ^ ((v >> 6) << 2); }

template<int KTOT>
__global__ __launch_bounds__(256, 4) void gemm64x256(
    const float* __restrict__ A, const float* __restrict__ Bm,
    const float* __restrict__ bias, float* __restrict__ C, int ldb, int ldc)
{
    __shared__ float As[32][64];
    __shared__ float Bs[32][256];
    const int tid = threadIdx.x;
    const int tx = tid & 31, ty = tid >> 5;
    const int n0 = blockIdx.x << 8;
    const int m0 = blockIdx.y << 6;
    const int sv0 = swz(tx << 3), sv1 = swz((tx << 3) + 4);
    float acc[8][8] = {};
    for (int k0 = 0; k0 < KTOT; k0 += 32) {
        __syncthreads();
        #pragma unroll
        for (int i = 0; i < 2; ++i) {
            int l = tid + (i << 8);
            int r = l >> 3, kq = (l & 7) << 2;
            float4 a = *(const float4*)&A[(size_t)(m0 + r) * KTOT + k0 + kq];
            As[kq + 0][r] = a.x; As[kq + 1][r] = a.y;
            As[kq + 2][r] = a.z; As[kq + 3][r] = a.w;
        }
        #pragma unroll
        for (int i = 0; i < 8; ++i) {
            int l = tid + (i << 8);
            int k = l >> 6, vq = (l & 63) << 2;
            *(float4*)&Bs[k][swz(vq)] =
                *(const float4*)&Bm[(size_t)(k0 + k) * ldb + n0 + vq];
        }
        __syncthreads();
        #pragma unroll
        for (int k = 0; k < 32; ++k) {
            float4 a0 = *(float4*)&As[k][ty << 3];
            float4 a1 = *(float4*)&As[k][(ty << 3) + 4];
            float4 b0 = *(float4*)&Bs[k][sv0];
            float4 b1 = *(float4*)&Bs[k][sv1];
            float av[8] = {a0.x,a0.y,a0.z,a0.w,a1.x,a1.y,a1.z,a1.w};
            float bv[8] = {b0.x,b0.y,b0.z,b0.w,b1.x,b1.y,b1.z,b1.w};
            #pragma unroll
            for (int i2 = 0; i2 < 8; ++i2)
                #pragma unroll
                for (int j = 0; j < 8; ++j)
                    acc[i2][j] = fmaf(av[i2], bv[j], acc[i2][j]);
        }
    }
    float4 bb0 = *(const float4*)&bias[n0 + (tx << 3)];
    float4 bb1 = *(const float4*)&bias[n0 + (tx << 3) + 4];
    float bv[8] = {bb0.x,bb0.y,bb0.z,bb0.w,bb1.x,bb1.y,bb1.z,bb1.w};
    #pragma unroll
    for (int i = 0; i < 8; ++i) {
        float4 o0 = make_float4(acc[i][0]+bv[0], acc[i][1]+bv[1],
                                acc[i][2]+bv[2], acc[i][3]+bv[3]);
        float4 o1 = make_float4(acc[i][4]+bv[4], acc[i][5]+bv[5],
                                acc[i][6]+bv[6], acc[i][7]+bv[7]);
        size_t base = (size_t)(m0 + (ty << 3) + i) * ldc + n0 + (tx << 3);
        *(float4*)&C[base]     = o0;
        *(float4*)&C[base + 4] = o1;
    }
}

// ---------------- GRU pointwise + emb gather + h bf16x3 split ---------------
__global__ __launch_bounds__(256) void gru_kernel(
    const int* __restrict__ syms, const float* __restrict__ emb,
    const float* __restrict__ gk, const float* __restrict__ b_in,
    const float* __restrict__ hm, const float* __restrict__ ph,
    unsigned short* __restrict__ h0, unsigned short* __restrict__ h1,
    unsigned short* __restrict__ h2, float* __restrict__ ht_out, int has_x)
{
    __shared__ float xsT[64][8];
    const int tid = threadIdx.x;
    const int row0 = blockIdx.x * 8;
    float az[8], ar[8], ah[8];
    const float bz = b_in[tid], br = b_in[256 + tid], bh = b_in[512 + tid];
    #pragma unroll
    for (int r = 0; r < 8; ++r) { az[r] = bz; ar[r] = br; ah[r] = bh; }
    if (has_x) {
        for (int l = tid; l < 512; l += 256) {
            int r = l >> 6, e = l & 63;
            xsT[e][r] = emb[(size_t)syms[row0 + r] * 64 + e];
        }
        __syncthreads();
        #pragma unroll 4
        for (int e = 0; e < 64; ++e) {
            float kz  = gk[e * 768 + tid];
            float kr_ = gk[e * 768 + 256 + tid];
            float kh  = gk[e * 768 + 512 + tid];
            float4 x0 = *(float4*)&xsT[e][0];
            float4 x1 = *(float4*)&xsT[e][4];
            float xv[8] = {x0.x, x0.y, x0.z, x0.w, x1.x, x1.y, x1.z, x1.w};
            #pragma unroll
            for (int r = 0; r < 8; ++r) {
                az[r] = fmaf(xv[r], kz, az[r]);
                ar[r] = fmaf(xv[r], kr_, ar[r]);
                ah[r] = fmaf(xv[r], kh, ah[r]);
            }
        }
    }
    #pragma unroll
    for (int r = 0; r < 8; ++r) {
        const int row = row0 + r;
        float hz  = hm[(size_t)row * 768 + tid];
        float hr  = hm[(size_t)row * 768 + 256 + tid];
        float hh  = hm[(size_t)row * 768 + 512 + tid];
        float phv = ph[(size_t)row * 256 + tid];
        float z  = 1.0f / (1.0f + expf(-(az[r] + hz)));
        float rr = 1.0f / (1.0f + expf(-(ar[r] + hr)));
        float ht = tanhf(ah[r] + rr * hh);
        float hv = z * phv + (1.0f - z) * ht;
        size_t idx = (size_t)row * 256 + tid;
        float bk;
        unsigned short u0 = bf16_rtne(hv, bk); float r1 = hv - bk;
        unsigned short u1 = bf16_rtne(r1, bk); float r2 = r1 - bk;
        float d; unsigned short u2 = bf16_rtne(r2, d);
        h0[idx] = u0; h1[idx] = u1; h2[idx] = u2;
        if (ht_out) ht_out[idx] = hv;
    }
}

// ---------------- logits: 128x128 MFMA tile + online softmax ----------------
// 4 waves (2x2), per wave 64x64 = 4x4 fragments of 16x16x32 bf16.
// LDS: A[3][128 rows][32 k] + B same, XOR-swizzled 16B slots, 48 KB.
__global__ __launch_bounds__(256, 3) void logits_mfma(
    const unsigned short* __restrict__ h0, const unsigned short* __restrict__ h1,
    const unsigned short* __restrict__ h2, const unsigned short* __restrict__ w0,
    const unsigned short* __restrict__ w1, const unsigned short* __restrict__ w2,
    const float* __restrict__ bo, float4* __restrict__ pstats)
{
    __shared__ char lds[49152];           // A: 0..24575, B: 24576..49151
    const int tid = threadIdx.x;
    const int m0 = blockIdx.y << 7, n0 = blockIdx.x << 7;
    const int w = tid >> 6, lane = tid & 63;
    const int c16 = lane & 15, rg = lane >> 4;
    const int arow0 = (w >> 1) * 64, brow0 = (w & 1) * 64;

    f32x4 acc[4][4] = {};

    for (int k0 = 0; k0 < 256; k0 += 32) {
        __syncthreads();
        uint4 va[3][2], vb[3][2];
        #pragma unroll
        for (int cc = 0; cc < 3; ++cc) {
            const unsigned short* hp = (cc == 0) ? h0 : ((cc == 1) ? h1 : h2);
            const unsigned short* wp = (cc == 0) ? w0 : ((cc == 1) ? w1 : w2);
            #pragma unroll
            for (int hh = 0; hh < 2; ++hh) {
                int rem = tid + (hh << 8);
                int row = rem >> 2, sl = rem & 3;
                va[cc][hh] = *(const uint4*)&hp[(size_t)(m0 + row) * 256 + k0 + sl * 8];
                vb[cc][hh] = *(const uint4*)&wp[(size_t)(n0 + row) * 256 + k0 + sl * 8];
            }
        }
        #pragma unroll
        for (int cc = 0; cc < 3; ++cc) {
            #pragma unroll
            for (int hh = 0; hh < 2; ++hh) {
                int rem = tid + (hh << 8);
                int row = rem >> 2, sl = rem & 3;
                int off = cc * 8192 + row * 64 + ((sl ^ ((row >> 1) & 3)) << 4);
                *(uint4*)&lds[off]         = va[cc][hh];
                *(uint4*)&lds[24576 + off] = vb[cc][hh];
            }
        }
        __syncthreads();

        short8v bfr[3][4];
        #pragma unroll
        for (int j = 0; j < 4; ++j) {
            int row = brow0 + j * 16 + c16;
            int off = 24576 + row * 64 + ((rg ^ ((row >> 1) & 3)) << 4);
            bfr[0][j] = *(short8v*)&lds[off];
            bfr[1][j] = *(short8v*)&lds[off + 8192];
            bfr[2][j] = *(short8v*)&lds[off + 16384];
        }
        #pragma unroll
        for (int i = 0; i < 4; ++i) {
            int row = arow0 + i * 16 + c16;
            int off = row * 64 + ((rg ^ ((row >> 1) & 3)) << 4);
            short8v a0 = *(short8v*)&lds[off];
            short8v a1 = *(short8v*)&lds[off + 8192];
            short8v a2 = *(short8v*)&lds[off + 16384];
            #pragma unroll
            for (int j = 0; j < 4; ++j) {
                f32x4 c = acc[i][j];
                c = __builtin_amdgcn_mfma_f32_16x16x32_bf16(a0, bfr[0][j], c, 0, 0, 0);
                c = __builtin_amdgcn_mfma_f32_16x16x32_bf16(a0, bfr[1][j], c, 0, 0, 0);
                c = __builtin_amdgcn_mfma_f32_16x16x32_bf16(a1, bfr[0][j], c, 0, 0, 0);
                c = __builtin_amdgcn_mfma_f32_16x16x32_bf16(a0, bfr[2][j], c, 0, 0, 0);
                c = __builtin_amdgcn_mfma_f32_16x16x32_bf16(a1, bfr[1][j], c, 0, 0, 0);
                c = __builtin_amdgcn_mfma_f32_16x16x32_bf16(a2, bfr[0][j], c, 0, 0, 0);
                acc[i][j] = c;
            }
        }
    }

    // epilogue: bias + per-row online softmax stats over this wave's 64 cols
    const int wn0 = n0 + brow0;
    float bov[4];
    #pragma unroll
    for (int j = 0; j < 4; ++j) bov[j] = bo[wn0 + j * 16 + c16];
    #pragma unroll
    for (int i = 0; i < 4; ++i) {
        #pragma unroll
        for (int reg = 0; reg < 4; ++reg) {
            int grow = m0 + arow0 + i * 16 + rg * 4 + reg;
            float m = -INFINITY, s = 0.f, q = 0.f; int am = 0;
            #pragma unroll
            for (int j = 0; j < 4; ++j) {     // cols ascending for fixed lane
                float l = acc[i][j][reg] + bov[j];
                if (l > m) {
                    float f = expf(m - l);
                    s = fmaf(s, f, 1.0f);
                    q = fmaf(q, f, l);
                    m = l; am = wn0 + j * 16 + c16;
                } else {
                    float e = expf(l - m);
                    s += e; q = fmaf(l, e, q);
                }
            }
            #pragma unroll
            for (int off = 1; off < 16; off <<= 1) {   // merge 16 c16-lanes
                float m2 = __shfl_xor(m, off);
                float s2 = __shfl_xor(s, off);
                float q2 = __shfl_xor(q, off);
                int   a2 = __shfl_xor(am, off);
                float M = fmaxf(m, m2);
                float f1 = expf(m - M), f2 = expf(m2 - M);
                s = s * f1 + s2 * f2;
                q = q * f1 + q2 * f2;
                am = (m > m2) ? am : ((m2 > m) ? a2 : (am < a2 ? am : a2));
                m = M;
            }
            if (c16 == 0)
                pstats[(size_t)(blockIdx.x * 2 + (w & 1)) * 8192 + grow] =
                    make_float4(m, s, q, __int_as_float(am));
        }
    }
}

// ---------------- finalize: merge 64 col-panel partials, outputs ------------
__global__ __launch_bounds__(64) void finalize_kernel(
    const float4* __restrict__ pstats, int* __restrict__ syms,
    float* __restrict__ out_seq, float* __restrict__ out_sel,
    float* __restrict__ out_ent, float* __restrict__ out_ml, int t, int last)
{
    const int row = blockIdx.x * 64 + threadIdx.x;
    float M = -INFINITY, S = 0.f, Q = 0.f; int A = 0;
    #pragma unroll 8
    for (int p = 0; p < 64; ++p) {              // col-ascending: ties keep lower A
        float4 pp = pstats[(size_t)p * 8192 + row];
        float m2 = pp.x, s2 = pp.y, q2 = pp.z; int a2 = __float_as_int(pp.w);
        if (m2 > M) {
            float f = expf(M - m2);
            S = S * f + s2; Q = Q * f + q2; M = m2; A = a2;
        } else {
            float f = expf(m2 - M);
            S = fmaf(s2, f, S); Q = fmaf(q2, f, Q);
        }
    }
    float lse = M + logf(S);
    float sel = M - lse;
    float ent = lse - Q / S;
    out_seq[(size_t)row * 6 + t] = (float)A;
    out_sel[(size_t)row * 6 + t] = sel;
    float ea = (t == 0) ? ent : (out_ent[row] + ent);
    out_ent[row] = last ? ea * (1.0f / 6.0f) : ea;
    if (t == 0) out_ml[row] = 6.0f;
    syms[row] = A;
}

// ---------------------------------------------------------------------------
extern "C" void kernel_launch(void* const* d_in, const int* in_sizes, int n_in,
                              void* d_out, int out_size, void* d_ws, size_t ws_size,
                              hipStream_t stream) {
    const float* vis  = (const float*)d_in[0];
    const float* Wv   = (const float*)d_in[1];
    const float* bv   = (const float*)d_in[2];
    const float* gk   = (const float*)d_in[3];
    const float* grk  = (const float*)d_in[4];
    const float* bin  = (const float*)d_in[5];
    const float* brec = (const float*)d_in[6];
    const float* Wo   = (const float*)d_in[7];
    const float* bo   = (const float*)d_in[8];
    const float* emb  = (const float*)d_in[9];

    float* out = (float*)d_out;
    float* out_seq = out;                 // (8192, 6)
    float* out_sel = out + 49152;         // (8192, 6)
    float* out_ent = out + 98304;         // (8192,)
    float* out_ml  = out + 106496;        // (8192,)
    float* out_ht  = out + 114688;        // (8192, 256)

    char* ws = (char*)d_ws;
    float*          ph     = (float*)(ws);                     // 8 MB
    float*          hm     = (float*)(ws + 8388608);           // 24 MB
    unsigned short* h0     = (unsigned short*)(ws + 33554432); // 4 MB
    unsigned short* h1     = (unsigned short*)(ws + 37748736); // 4 MB
    unsigned short* h2     = (unsigned short*)(ws + 41943040); // 4 MB
    unsigned short* w0     = (unsigned short*)(ws + 46137344); // 2 MB
    unsigned short* w1     = (unsigned short*)(ws + 48234496); // 2 MB
    unsigned short* w2     = (unsigned short*)(ws + 50331648); // 2 MB
    float4*         pstats = (float4*)(ws + 52428800);         // 8 MB
    int*            syms   = (int*)(ws + 60817408);            // 32 KB

    // one-time: Wo -> transposed bf16x3 splits
    prep_wot<<<dim3(64, 4), 256, 0, stream>>>(Wo, w0, w1, w2);
    // K1: prev_hidden = vis @ Wv + bv
    gemm64x256<512><<<dim3(1, 128), 256, 0, stream>>>(vis, Wv, bv, ph, 256, 256);
    // K2: hm = prev_hidden @ grk + brec (loop-invariant)
    gemm64x256<256><<<dim3(3, 128), 256, 0, stream>>>(ph, grk, brec, hm, 768, 768);

    for (int t = 0; t < 6; ++t) {
        gru_kernel<<<1024, 256, 0, stream>>>(syms, emb, gk, bin, hm, ph,
                                             h0, h1, h2,
                                             (t == 5) ? out_ht : nullptr,
                                             (t > 0) ? 1 : 0);
        logits_mfma<<<dim3(32, 64), 256, 0, stream>>>(h0, h1, h2, w0, w1, w2,
                                                      bo, pstats);
        finalize_kernel<<<128, 64, 0, stream>>>(pstats, syms, out_seq, out_sel,
                                                out_ent, out_ml, t, (t == 5) ? 1 : 0);
    }
}

// Round 4
// 753.323 us; speedup vs baseline: 3.2010x; 1.6778x over previous
//
#include <hip/hip_runtime.h>
#include <hip/hip_fp16.h>
#include <math.h>

// ---------------------------------------------------------------------------
// Sender model, MI355X, round 4.
// Logits GEMM: fp16x2 (Markidis) split, 3 MFMA products, fp32 accumulate.
// Staging via global_load_lds (linear LDS dest, swizzle folded into per-lane
// global source). Epilogue: raw (unshifted) softmax stats + DPP reductions.
// ---------------------------------------------------------------------------

typedef __attribute__((ext_vector_type(8))) _Float16 half8v;  // 16 B
typedef __attribute__((ext_vector_type(4))) float f32x4;

// conflict-free-enough slot swizzle (2-way residual = free, m136)
__device__ __forceinline__ int lds_off(int row, int slot) {
    return (row << 6) + ((slot ^ (row & 3) ^ ((row >> 2) & 3)) << 4);
}

__device__ __forceinline__ void gld_lds16(const void* src, void* dst) {
    __builtin_amdgcn_global_load_lds(
        (const __attribute__((address_space(1))) void*)src,
        (__attribute__((address_space(3))) void*)dst, 16, 0, 0);
}

template<int C>
__device__ __forceinline__ float dppf(float x) {
    return __builtin_bit_cast(float, __builtin_amdgcn_update_dpp(
        __builtin_bit_cast(int, x), __builtin_bit_cast(int, x), C, 0xF, 0xF, false));
}
template<int C>
__device__ __forceinline__ int dppi(int x) {
    return __builtin_amdgcn_update_dpp(x, x, C, 0xF, 0xF, false);
}

// ---------------- one-time: Wo[k][n] -> fp16x2 splits, n-major k-contig -----
__global__ __launch_bounds__(256) void prep_wot(
    const float* __restrict__ Wo, unsigned short* __restrict__ w0,
    unsigned short* __restrict__ w1)
{
    __shared__ float Ts[64][65];
    const int tid = threadIdx.x;
    const int n0 = blockIdx.x * 64, k0 = blockIdx.y * 64;
    const int ty = tid >> 2, tx = tid & 3;
    #pragma unroll
    for (int q = 0; q < 4; ++q) {
        float4 v = *(const float4*)&Wo[(size_t)(k0 + ty) * 4096 + n0 + tx * 16 + q * 4];
        Ts[ty][tx * 16 + q * 4 + 0] = v.x; Ts[ty][tx * 16 + q * 4 + 1] = v.y;
        Ts[ty][tx * 16 + q * 4 + 2] = v.z; Ts[ty][tx * 16 + q * 4 + 3] = v.w;
    }
    __syncthreads();
    #pragma unroll
    for (int ii = 0; ii < 2; ++ii) {
        int item = tid + (ii << 8);          // 0..511
        int n = item >> 3, g = item & 7;     // n 0..63, k-group 0..7
        unsigned short u0[8], u1[8];
        #pragma unroll
        for (int e = 0; e < 8; ++e) {
            float v = Ts[g * 8 + e][n];
            __half a = __float2half(v);
            float f = __half2float(a);
            __half b = __float2half(v - f);
            u0[e] = __half_as_ushort(a);
            u1[e] = __half_as_ushort(b);
        }
        size_t base = (size_t)(n0 + n) * 256 + k0 + g * 8;
        *(uint4*)&w0[base] = *(uint4*)u0;
        *(uint4*)&w1[base] = *(uint4*)u1;
    }
}

// ---------------- fp32 GEMM (K1/K2): C[M,N]=A@B+bias ------------------------
__device__ __forceinline__ int swz(int v) { return v ^ ((v >> 6) << 2); }

template<int KTOT>
__global__ __launch_bounds__(256, 4) void gemm64x256(
    const float* __restrict__ A, const float* __restrict__ Bm,
    const float* __restrict__ bias, float* __restrict__ C, int ldb, int ldc)
{
    __shared__ float As[32][64];
    __shared__ float Bs[32][256];
    const int tid = threadIdx.x;
    const int tx = tid & 31, ty = tid >> 5;
    const int n0 = blockIdx.x << 8;
    const int m0 = blockIdx.y << 6;
    const int sv0 = swz(tx << 3), sv1 = swz((tx << 3) + 4);
    float acc[8][8] = {};
    for (int k0 = 0; k0 < KTOT; k0 += 32) {
        __syncthreads();
        #pragma unroll
        for (int i = 0; i < 2; ++i) {
            int l = tid + (i << 8);
            int r = l >> 3, kq = (l & 7) << 2;
            float4 a = *(const float4*)&A[(size_t)(m0 + r) * KTOT + k0 + kq];
            As[kq + 0][r] = a.x; As[kq + 1][r] = a.y;
            As[kq + 2][r] = a.z; As[kq + 3][r] = a.w;
        }
        #pragma unroll
        for (int i = 0; i < 8; ++i) {
            int l = tid + (i << 8);
            int k = l >> 6, vq = (l & 63) << 2;
            *(float4*)&Bs[k][swz(vq)] =
                *(const float4*)&Bm[(size_t)(k0 + k) * ldb + n0 + vq];
        }
        __syncthreads();
        #pragma unroll
        for (int k = 0; k < 32; ++k) {
            float4 a0 = *(float4*)&As[k][ty << 3];
            float4 a1 = *(float4*)&As[k][(ty << 3) + 4];
            float4 b0 = *(float4*)&Bs[k][sv0];
            float4 b1 = *(float4*)&Bs[k][sv1];
            float av[8] = {a0.x,a0.y,a0.z,a0.w,a1.x,a1.y,a1.z,a1.w};
            float bv[8] = {b0.x,b0.y,b0.z,b0.w,b1.x,b1.y,b1.z,b1.w};
            #pragma unroll
            for (int i2 = 0; i2 < 8; ++i2)
                #pragma unroll
                for (int j = 0; j < 8; ++j)
                    acc[i2][j] = fmaf(av[i2], bv[j], acc[i2][j]);
        }
    }
    float4 bb0 = *(const float4*)&bias[n0 + (tx << 3)];
    float4 bb1 = *(const float4*)&bias[n0 + (tx << 3) + 4];
    float bv[8] = {bb0.x,bb0.y,bb0.z,bb0.w,bb1.x,bb1.y,bb1.z,bb1.w};
    #pragma unroll
    for (int i = 0; i < 8; ++i) {
        float4 o0 = make_float4(acc[i][0]+bv[0], acc[i][1]+bv[1],
                                acc[i][2]+bv[2], acc[i][3]+bv[3]);
        float4 o1 = make_float4(acc[i][4]+bv[4], acc[i][5]+bv[5],
                                acc[i][6]+bv[6], acc[i][7]+bv[7]);
        size_t base = (size_t)(m0 + (ty << 3) + i) * ldc + n0 + (tx << 3);
        *(float4*)&C[base]     = o0;
        *(float4*)&C[base + 4] = o1;
    }
}

// ---------------- GRU pointwise + emb gather + h fp16x2 split ---------------
__global__ __launch_bounds__(256) void gru_kernel(
    const int* __restrict__ syms, const float* __restrict__ emb,
    const float* __restrict__ gk, const float* __restrict__ b_in,
    const float* __restrict__ hm, const float* __restrict__ ph,
    unsigned short* __restrict__ h0, unsigned short* __restrict__ h1,
    float* __restrict__ ht_out, int has_x)
{
    __shared__ float xsT[64][8];
    const int tid = threadIdx.x;
    const int row0 = blockIdx.x * 8;
    float az[8], ar[8], ah[8];
    const float bz = b_in[tid], br = b_in[256 + tid], bh = b_in[512 + tid];
    #pragma unroll
    for (int r = 0; r < 8; ++r) { az[r] = bz; ar[r] = br; ah[r] = bh; }
    if (has_x) {
        for (int l = tid; l < 512; l += 256) {
            int r = l >> 6, e = l & 63;
            xsT[e][r] = emb[(size_t)syms[row0 + r] * 64 + e];
        }
        __syncthreads();
        #pragma unroll 4
        for (int e = 0; e < 64; ++e) {
            float kz  = gk[e * 768 + tid];
            float kr_ = gk[e * 768 + 256 + tid];
            float kh  = gk[e * 768 + 512 + tid];
            float4 x0 = *(float4*)&xsT[e][0];
            float4 x1 = *(float4*)&xsT[e][4];
            float xv[8] = {x0.x, x0.y, x0.z, x0.w, x1.x, x1.y, x1.z, x1.w};
            #pragma unroll
            for (int r = 0; r < 8; ++r) {
                az[r] = fmaf(xv[r], kz, az[r]);
                ar[r] = fmaf(xv[r], kr_, ar[r]);
                ah[r] = fmaf(xv[r], kh, ah[r]);
            }
        }
    }
    #pragma unroll
    for (int r = 0; r < 8; ++r) {
        const int row = row0 + r;
        float hz  = hm[(size_t)row * 768 + tid];
        float hr  = hm[(size_t)row * 768 + 256 + tid];
        float hh  = hm[(size_t)row * 768 + 512 + tid];
        float phv = ph[(size_t)row * 256 + tid];
        float z  = 1.0f / (1.0f + expf(-(az[r] + hz)));
        float rr = 1.0f / (1.0f + expf(-(ar[r] + hr)));
        float ht = tanhf(ah[r] + rr * hh);
        float hv = z * phv + (1.0f - z) * ht;
        size_t idx = (size_t)row * 256 + tid;
        __half a = __float2half(hv);
        float f = __half2float(a);
        __half b = __float2half(hv - f);
        h0[idx] = __half_as_ushort(a);
        h1[idx] = __half_as_ushort(b);
        if (ht_out) ht_out[idx] = hv;
    }
}

// ---------------- logits: 128x128 fp16x2 MFMA + raw softmax stats -----------
// 4 waves (2x2), wave tile 64x64 = 4x4 frags of 16x16x32 f16, 3 products.
// LDS: 2 bufs x { A0 8K | A1 8K | B0 8K | B1 8K } = 64 KB.
__global__ __launch_bounds__(256, 2) void logits_mfma(
    const unsigned short* __restrict__ h0, const unsigned short* __restrict__ h1,
    const unsigned short* __restrict__ w0, const unsigned short* __restrict__ w1,
    const float* __restrict__ bo, float4* __restrict__ pstats)
{
    __shared__ char lds[65536];
    const int tid = threadIdx.x;
    const int w = tid >> 6, lane = tid & 63;
    const int c16 = lane & 15, rg = lane >> 4;
    const int m0 = blockIdx.y << 7, n0 = blockIdx.x << 7;
    const int arow0 = (w >> 1) << 6, brow0 = (w & 1) << 6;

    // per-wave staging setup: wave w owns segment w (A0,A1,B0,B1)
    const unsigned short* segsrc = (w == 0) ? h0 : (w == 1) ? h1
                                 : (w == 2) ? w0 : w1;
    const int segrow0 = (w < 2) ? m0 : n0;

    f32x4 acc[4][4] = {};

    // stage K-step 0 into buf 0
    #pragma unroll
    for (int q = 0; q < 8; ++q) {
        int row = (q << 4) + (lane >> 2);
        int slot = (lane & 3) ^ (row & 3) ^ ((row >> 2) & 3);
        gld_lds16(segsrc + (size_t)(segrow0 + row) * 256 + (slot << 3),
                  &lds[(w << 13) + (q << 10)]);
    }
    asm volatile("s_waitcnt vmcnt(0)" ::: "memory");
    __syncthreads();

    for (int t = 0; t < 8; ++t) {
        const int base = (t & 1) << 15;
        if (t < 7) {                       // stage next K-step into other buf
            const int nbase = ((t + 1) & 1) << 15;
            const int k0n = (t + 1) << 5;
            #pragma unroll
            for (int q = 0; q < 8; ++q) {
                int row = (q << 4) + (lane >> 2);
                int slot = (lane & 3) ^ (row & 3) ^ ((row >> 2) & 3);
                gld_lds16(segsrc + (size_t)(segrow0 + row) * 256 + k0n + (slot << 3),
                          &lds[nbase + (w << 13) + (q << 10)]);
            }
        }
        // compute on current buffer
        half8v afr[4][2];
        #pragma unroll
        for (int i = 0; i < 4; ++i) {
            int o = lds_off(arow0 + (i << 4) + c16, rg);
            afr[i][0] = *(half8v*)&lds[base + o];
            afr[i][1] = *(half8v*)&lds[base + 8192 + o];
        }
        #pragma unroll
        for (int j = 0; j < 4; ++j) {
            int o = lds_off(brow0 + (j << 4) + c16, rg);
            half8v b0 = *(half8v*)&lds[base + 16384 + o];
            half8v b1 = *(half8v*)&lds[base + 24576 + o];
            #pragma unroll
            for (int i = 0; i < 4; ++i) {
                f32x4 c = acc[i][j];
                c = __builtin_amdgcn_mfma_f32_16x16x32_f16(afr[i][0], b0, c, 0, 0, 0);
                c = __builtin_amdgcn_mfma_f32_16x16x32_f16(afr[i][1], b0, c, 0, 0, 0);
                c = __builtin_amdgcn_mfma_f32_16x16x32_f16(afr[i][0], b1, c, 0, 0, 0);
                acc[i][j] = c;
            }
        }
        asm volatile("s_waitcnt vmcnt(0)" ::: "memory");
        __syncthreads();
    }

    // epilogue: raw softmax stats (no max shift -- logits bounded ~|8|),
    // DPP row_shl reductions across the 16 c16 lanes (zero LDS-port traffic).
    const int wn0 = n0 + brow0;
    float bov[4];
    #pragma unroll
    for (int j = 0; j < 4; ++j) bov[j] = bo[wn0 + j * 16 + c16];
    #pragma unroll
    for (int i = 0; i < 4; ++i) {
        #pragma unroll
        for (int reg = 0; reg < 4; ++reg) {
            float l0 = acc[i][0][reg] + bov[0];
            float l1 = acc[i][1][reg] + bov[1];
            float l2 = acc[i][2][reg] + bov[2];
            float l3 = acc[i][3][reg] + bov[3];
            // in-lane max + argmax (cols ascending, strict > keeps lowest)
            float m = l0; int a = wn0 + c16;
            if (l1 > m) { m = l1; a = wn0 + 16 + c16; }
            if (l2 > m) { m = l2; a = wn0 + 32 + c16; }
            if (l3 > m) { m = l3; a = wn0 + 48 + c16; }
            float e0 = __expf(l0), e1 = __expf(l1), e2 = __expf(l2), e3 = __expf(l3);
            float s = (e0 + e1) + (e2 + e3);
            float q = fmaf(l0, e0, fmaf(l1, e1, fmaf(l2, e2, l3 * e3)));
            // 16-lane DPP reductions (valid in lane c16==0)
            s += dppf<0x108>(s); s += dppf<0x104>(s);
            s += dppf<0x102>(s); s += dppf<0x101>(s);
            q += dppf<0x108>(q); q += dppf<0x104>(q);
            q += dppf<0x102>(q); q += dppf<0x101>(q);
            #define MMERGE(C) { float m2 = dppf<C>(m); int a2 = dppi<C>(a); \
                bool bt = (m2 > m) || (m2 == m && a2 < a); \
                m = bt ? m2 : m; a = bt ? a2 : a; }
            MMERGE(0x108) MMERGE(0x104) MMERGE(0x102) MMERGE(0x101)
            #undef MMERGE
            if (c16 == 0) {
                int grow = m0 + arow0 + (i << 4) + (rg << 2) + reg;
                pstats[(size_t)((blockIdx.x << 1) + (w & 1)) * 8192 + grow] =
                    make_float4(m, s, q, __int_as_float(a));
            }
        }
    }
}

// ---------------- finalize: plain-add merge of 64 panels, outputs -----------
__global__ __launch_bounds__(64) void finalize_kernel(
    const float4* __restrict__ pstats, int* __restrict__ syms,
    float* __restrict__ out_seq, float* __restrict__ out_sel,
    float* __restrict__ out_ent, float* __restrict__ out_ml, int t, int last)
{
    const int row = blockIdx.x * 64 + threadIdx.x;
    float M = -INFINITY, S = 0.f, Q = 0.f; int A = 0;
    #pragma unroll 8
    for (int p = 0; p < 64; ++p) {
        float4 pp = pstats[(size_t)p * 8192 + row];
        S += pp.y; Q += pp.z;
        int a2 = __float_as_int(pp.w);
        if (pp.x > M || (pp.x == M && a2 < A)) { M = pp.x; A = a2; }
    }
    float lse = logf(S);
    float sel = M - lse;
    float ent = lse - Q / S;
    out_seq[(size_t)row * 6 + t] = (float)A;
    out_sel[(size_t)row * 6 + t] = sel;
    float ea = (t == 0) ? ent : (out_ent[row] + ent);
    out_ent[row] = last ? ea * (1.0f / 6.0f) : ea;
    if (t == 0) out_ml[row] = 6.0f;
    syms[row] = A;
}

// ---------------------------------------------------------------------------
extern "C" void kernel_launch(void* const* d_in, const int* in_sizes, int n_in,
                              void* d_out, int out_size, void* d_ws, size_t ws_size,
                              hipStream_t stream) {
    const float* vis  = (const float*)d_in[0];
    const float* Wv   = (const float*)d_in[1];
    const float* bv   = (const float*)d_in[2];
    const float* gk   = (const float*)d_in[3];
    const float* grk  = (const float*)d_in[4];
    const float* bin  = (const float*)d_in[5];
    const float* brec = (const float*)d_in[6];
    const float* Wo   = (const float*)d_in[7];
    const float* bo   = (const float*)d_in[8];
    const float* emb  = (const float*)d_in[9];

    float* out = (float*)d_out;
    float* out_seq = out;                 // (8192, 6)
    float* out_sel = out + 49152;         // (8192, 6)
    float* out_ent = out + 98304;         // (8192,)
    float* out_ml  = out + 106496;        // (8192,)
    float* out_ht  = out + 114688;        // (8192, 256)

    char* ws = (char*)d_ws;
    float*          ph     = (float*)(ws);                      // 8 MB
    float*          hm     = (float*)(ws + 8388608);            // 24 MB
    unsigned short* h0     = (unsigned short*)(ws + 33554432);  // 4 MB
    unsigned short* h1     = (unsigned short*)(ws + 37748736);  // 4 MB
    unsigned short* w0     = (unsigned short*)(ws + 41943040);  // 2 MB
    unsigned short* w1     = (unsigned short*)(ws + 44040192);  // 2 MB
    float4*         pstats = (float4*)(ws + 46137344);          // 8 MB
    int*            syms   = (int*)(ws + 54525952);             // 32 KB

    // one-time: Wo -> transposed fp16x2 splits
    prep_wot<<<dim3(64, 4), 256, 0, stream>>>(Wo, w0, w1);
    // K1: prev_hidden = vis @ Wv + bv
    gemm64x256<512><<<dim3(1, 128), 256, 0, stream>>>(vis, Wv, bv, ph, 256, 256);
    // K2: hm = prev_hidden @ grk + brec (loop-invariant)
    gemm64x256<256><<<dim3(3, 128), 256, 0, stream>>>(ph, grk, brec, hm, 768, 768);

    for (int t = 0; t < 6; ++t) {
        gru_kernel<<<1024, 256, 0, stream>>>(syms, emb, gk, bin, hm, ph,
                                             h0, h1,
                                             (t == 5) ? out_ht : nullptr,
                                             (t > 0) ? 1 : 0);
        logits_mfma<<<dim3(32, 64), 256, 0, stream>>>(h0, h1, w0, w1, bo, pstats);
        finalize_kernel<<<128, 64, 0, stream>>>(pstats, syms, out_seq, out_sel,
                                                out_ent, out_ml, t, (t == 5) ? 1 : 0);
    }
}

// Round 5
// 682.026 us; speedup vs baseline: 3.5356x; 1.1045x over previous
//
#include <hip/hip_runtime.h>
#include <hip/hip_fp16.h>
#include <math.h>

// ---------------------------------------------------------------------------
// Sender model, MI355X, round 5.
// All three GEMMs (K1 prev_hidden, K2 hm, logits) on fp16x2 (Markidis) MFMA:
// 3 products (A0B0, A1B0, A0B1), fp32 accumulate, ~2^-22 rel error.
// Staging via global_load_lds, swizzle folded into per-lane global source.
// Epilogue of logits: raw softmax stats + DPP reductions (no LDS traffic).
// ---------------------------------------------------------------------------

typedef __attribute__((ext_vector_type(8))) _Float16 half8v;  // 16 B
typedef __attribute__((ext_vector_type(4))) float f32x4;

// conflict-free-enough slot swizzle (2-way residual = free, m136); row stride 64 B
__device__ __forceinline__ int lds_off(int row, int slot) {
    return (row << 6) + ((slot ^ (row & 3) ^ ((row >> 2) & 3)) << 4);
}

__device__ __forceinline__ void gld_lds16(const void* src, void* dst) {
    __builtin_amdgcn_global_load_lds(
        (const __attribute__((address_space(1))) void*)src,
        (__attribute__((address_space(3))) void*)dst, 16, 0, 0);
}

template<int C>
__device__ __forceinline__ float dppf(float x) {
    return __builtin_bit_cast(float, __builtin_amdgcn_update_dpp(
        __builtin_bit_cast(int, x), __builtin_bit_cast(int, x), C, 0xF, 0xF, false));
}
template<int C>
__device__ __forceinline__ int dppi(int x) {
    return __builtin_amdgcn_update_dpp(x, x, C, 0xF, 0xF, false);
}

__device__ __forceinline__ void f16split(float v, unsigned short& u0,
                                         unsigned short& u1) {
    __half a = __float2half(v);            // RTNE
    float f = __half2float(a);
    __half b = __float2half(v - f);
    u0 = __half_as_ushort(a);
    u1 = __half_as_ushort(b);
}

// ---------------- elementwise fp16x2 split (vis, ph) ------------------------
__global__ __launch_bounds__(256) void split_ew(
    const float* __restrict__ in, unsigned short* __restrict__ o0,
    unsigned short* __restrict__ o1, int n4)
{
    int i = blockIdx.x * 256 + threadIdx.x;
    if (i >= n4) return;
    float4 v = *(const float4*)&in[(size_t)i * 4];
    unsigned short a[4], b[4];
    f16split(v.x, a[0], b[0]); f16split(v.y, a[1], b[1]);
    f16split(v.z, a[2], b[2]); f16split(v.w, a[3], b[3]);
    *(uint2*)&o0[(size_t)i * 4] = *(uint2*)a;
    *(uint2*)&o1[(size_t)i * 4] = *(uint2*)b;
}

// ---------------- W[K][N] -> [n][k] fp16x2 splits (Wo, Wv, grk) -------------
__global__ __launch_bounds__(256) void trans_split(
    const float* __restrict__ W, unsigned short* __restrict__ o0,
    unsigned short* __restrict__ o1, int N, int K)
{
    __shared__ float Ts[64][65];
    const int tid = threadIdx.x;
    const int n0 = blockIdx.x * 64, k0 = blockIdx.y * 64;
    const int ty = tid >> 2, tx = tid & 3;
    #pragma unroll
    for (int q = 0; q < 4; ++q) {
        float4 v = *(const float4*)&W[(size_t)(k0 + ty) * N + n0 + tx * 16 + q * 4];
        Ts[ty][tx * 16 + q * 4 + 0] = v.x; Ts[ty][tx * 16 + q * 4 + 1] = v.y;
        Ts[ty][tx * 16 + q * 4 + 2] = v.z; Ts[ty][tx * 16 + q * 4 + 3] = v.w;
    }
    __syncthreads();
    #pragma unroll
    for (int ii = 0; ii < 2; ++ii) {
        int item = tid + (ii << 8);          // 0..511
        int n = item >> 3, g = item & 7;     // n 0..63, k-group 0..7
        unsigned short u0[8], u1[8];
        #pragma unroll
        for (int e = 0; e < 8; ++e)
            f16split(Ts[g * 8 + e][n], u0[e], u1[e]);
        size_t base = (size_t)(n0 + n) * K + k0 + g * 8;
        *(uint4*)&o0[base] = *(uint4*)u0;
        *(uint4*)&o1[base] = *(uint4*)u1;
    }
}

// ---------------- fp16x2 MFMA GEMM, 64x64 tile (K1, K2) ---------------------
// 4 waves (2x2), wave tile 32x32 = 2x2 frags of 16x16x32 f16, 3 products.
// LDS: 2 bufs x { A0 4K | A1 4K | B0 4K | B1 4K } = 32 KB -> 5 blocks/CU.
template<int KTOT>
__global__ __launch_bounds__(256, 4) void mfma_gemm(
    const unsigned short* __restrict__ a0s, const unsigned short* __restrict__ a1s,
    const unsigned short* __restrict__ b0s, const unsigned short* __restrict__ b1s,
    const float* __restrict__ bias, float* __restrict__ C, int ldc)
{
    __shared__ char lds[32768];
    const int tid = threadIdx.x;
    const int w = tid >> 6, lane = tid & 63;
    const int c16 = lane & 15, rg = lane >> 4;
    const int m0 = blockIdx.y << 6, n0 = blockIdx.x << 6;
    const int arow0 = (w >> 1) << 5, brow0 = (w & 1) << 5;

    const unsigned short* segsrc = (w == 0) ? a0s : (w == 1) ? a1s
                                 : (w == 2) ? b0s : b1s;
    const int segrow0 = (w < 2) ? m0 : n0;

    f32x4 acc[2][2] = {};

    #pragma unroll
    for (int q = 0; q < 4; ++q) {          // stage K-step 0 into buf 0
        int row = (q << 4) + (lane >> 2);
        int slot = (lane & 3) ^ (row & 3) ^ ((row >> 2) & 3);
        gld_lds16(segsrc + (size_t)(segrow0 + row) * KTOT + (slot << 3),
                  &lds[(w << 12) + (q << 10)]);
    }
    asm volatile("s_waitcnt vmcnt(0)" ::: "memory");
    __syncthreads();

    for (int t = 0; t < KTOT / 32; ++t) {
        const int base = (t & 1) << 14;
        if (t < KTOT / 32 - 1) {           // stage next K-step into other buf
            const int nbase = ((t + 1) & 1) << 14;
            const int k0n = (t + 1) << 5;
            #pragma unroll
            for (int q = 0; q < 4; ++q) {
                int row = (q << 4) + (lane >> 2);
                int slot = (lane & 3) ^ (row & 3) ^ ((row >> 2) & 3);
                gld_lds16(segsrc + (size_t)(segrow0 + row) * KTOT + k0n + (slot << 3),
                          &lds[nbase + (w << 12) + (q << 10)]);
            }
        }
        half8v afr[2][2], bfr[2][2];
        #pragma unroll
        for (int i = 0; i < 2; ++i) {
            int oa = lds_off(arow0 + (i << 4) + c16, rg);
            afr[i][0] = *(half8v*)&lds[base + oa];
            afr[i][1] = *(half8v*)&lds[base + 4096 + oa];
            int ob = lds_off(brow0 + (i << 4) + c16, rg);
            bfr[i][0] = *(half8v*)&lds[base + 8192 + ob];
            bfr[i][1] = *(half8v*)&lds[base + 12288 + ob];
        }
        #pragma unroll
        for (int i = 0; i < 2; ++i)
            #pragma unroll
            for (int j = 0; j < 2; ++j) {
                f32x4 c = acc[i][j];
                c = __builtin_amdgcn_mfma_f32_16x16x32_f16(afr[i][0], bfr[j][0], c, 0, 0, 0);
                c = __builtin_amdgcn_mfma_f32_16x16x32_f16(afr[i][1], bfr[j][0], c, 0, 0, 0);
                c = __builtin_amdgcn_mfma_f32_16x16x32_f16(afr[i][0], bfr[j][1], c, 0, 0, 0);
                acc[i][j] = c;
            }
        asm volatile("s_waitcnt vmcnt(0)" ::: "memory");
        __syncthreads();
    }

    #pragma unroll
    for (int j = 0; j < 2; ++j) {
        int col = n0 + brow0 + (j << 4) + c16;
        float bb = bias[col];
        #pragma unroll
        for (int i = 0; i < 2; ++i)
            #pragma unroll
            for (int reg = 0; reg < 4; ++reg) {
                int row = m0 + arow0 + (i << 4) + (rg << 2) + reg;
                C[(size_t)row * ldc + col] = acc[i][j][reg] + bb;
            }
    }
}

// ---------------- GRU pointwise + emb gather + h fp16x2 split ---------------
__global__ __launch_bounds__(256) void gru_kernel(
    const int* __restrict__ syms, const float* __restrict__ emb,
    const float* __restrict__ gk, const float* __restrict__ b_in,
    const float* __restrict__ hm, const float* __restrict__ ph,
    unsigned short* __restrict__ h0, unsigned short* __restrict__ h1,
    float* __restrict__ ht_out, int has_x)
{
    __shared__ float xsT[64][8];
    const int tid = threadIdx.x;
    const int row0 = blockIdx.x * 8;
    float az[8], ar[8], ah[8];
    const float bz = b_in[tid], br = b_in[256 + tid], bh = b_in[512 + tid];
    #pragma unroll
    for (int r = 0; r < 8; ++r) { az[r] = bz; ar[r] = br; ah[r] = bh; }
    if (has_x) {
        for (int l = tid; l < 512; l += 256) {
            int r = l >> 6, e = l & 63;
            xsT[e][r] = emb[(size_t)syms[row0 + r] * 64 + e];
        }
        __syncthreads();
        #pragma unroll 4
        for (int e = 0; e < 64; ++e) {
            float kz  = gk[e * 768 + tid];
            float kr_ = gk[e * 768 + 256 + tid];
            float kh  = gk[e * 768 + 512 + tid];
            float4 x0 = *(float4*)&xsT[e][0];
            float4 x1 = *(float4*)&xsT[e][4];
            float xv[8] = {x0.x, x0.y, x0.z, x0.w, x1.x, x1.y, x1.z, x1.w};
            #pragma unroll
            for (int r = 0; r < 8; ++r) {
                az[r] = fmaf(xv[r], kz, az[r]);
                ar[r] = fmaf(xv[r], kr_, ar[r]);
                ah[r] = fmaf(xv[r], kh, ah[r]);
            }
        }
    }
    #pragma unroll
    for (int r = 0; r < 8; ++r) {
        const int row = row0 + r;
        float hz  = hm[(size_t)row * 768 + tid];
        float hr  = hm[(size_t)row * 768 + 256 + tid];
        float hh  = hm[(size_t)row * 768 + 512 + tid];
        float phv = ph[(size_t)row * 256 + tid];
        float z  = 1.0f / (1.0f + expf(-(az[r] + hz)));
        float rr = 1.0f / (1.0f + expf(-(ar[r] + hr)));
        float ht = tanhf(ah[r] + rr * hh);
        float hv = z * phv + (1.0f - z) * ht;
        size_t idx = (size_t)row * 256 + tid;
        unsigned short u0, u1;
        f16split(hv, u0, u1);
        h0[idx] = u0; h1[idx] = u1;
        if (ht_out) ht_out[idx] = hv;
    }
}

// ---------------- logits: 128x128 fp16x2 MFMA + raw softmax stats -----------
// 4 waves (2x2), wave tile 64x64 = 4x4 frags of 16x16x32 f16, 3 products.
// LDS: 2 bufs x { A0 8K | A1 8K | B0 8K | B1 8K } = 64 KB.
__global__ __launch_bounds__(256, 2) void logits_mfma(
    const unsigned short* __restrict__ h0, const unsigned short* __restrict__ h1,
    const unsigned short* __restrict__ w0, const unsigned short* __restrict__ w1,
    const float* __restrict__ bo, float4* __restrict__ pstats)
{
    __shared__ char lds[65536];
    const int tid = threadIdx.x;
    const int w = tid >> 6, lane = tid & 63;
    const int c16 = lane & 15, rg = lane >> 4;
    const int m0 = blockIdx.y << 7, n0 = blockIdx.x << 7;
    const int arow0 = (w >> 1) << 6, brow0 = (w & 1) << 6;

    const unsigned short* segsrc = (w == 0) ? h0 : (w == 1) ? h1
                                 : (w == 2) ? w0 : w1;
    const int segrow0 = (w < 2) ? m0 : n0;

    f32x4 acc[4][4] = {};

    #pragma unroll
    for (int q = 0; q < 8; ++q) {          // stage K-step 0 into buf 0
        int row = (q << 4) + (lane >> 2);
        int slot = (lane & 3) ^ (row & 3) ^ ((row >> 2) & 3);
        gld_lds16(segsrc + (size_t)(segrow0 + row) * 256 + (slot << 3),
                  &lds[(w << 13) + (q << 10)]);
    }
    asm volatile("s_waitcnt vmcnt(0)" ::: "memory");
    __syncthreads();

    for (int t = 0; t < 8; ++t) {
        const int base = (t & 1) << 15;
        if (t < 7) {                       // stage next K-step into other buf
            const int nbase = ((t + 1) & 1) << 15;
            const int k0n = (t + 1) << 5;
            #pragma unroll
            for (int q = 0; q < 8; ++q) {
                int row = (q << 4) + (lane >> 2);
                int slot = (lane & 3) ^ (row & 3) ^ ((row >> 2) & 3);
                gld_lds16(segsrc + (size_t)(segrow0 + row) * 256 + k0n + (slot << 3),
                          &lds[nbase + (w << 13) + (q << 10)]);
            }
        }
        half8v afr[4][2];
        #pragma unroll
        for (int i = 0; i < 4; ++i) {
            int o = lds_off(arow0 + (i << 4) + c16, rg);
            afr[i][0] = *(half8v*)&lds[base + o];
            afr[i][1] = *(half8v*)&lds[base + 8192 + o];
        }
        #pragma unroll
        for (int j = 0; j < 4; ++j) {
            int o = lds_off(brow0 + (j << 4) + c16, rg);
            half8v b0 = *(half8v*)&lds[base + 16384 + o];
            half8v b1 = *(half8v*)&lds[base + 24576 + o];
            #pragma unroll
            for (int i = 0; i < 4; ++i) {
                f32x4 c = acc[i][j];
                c = __builtin_amdgcn_mfma_f32_16x16x32_f16(afr[i][0], b0, c, 0, 0, 0);
                c = __builtin_amdgcn_mfma_f32_16x16x32_f16(afr[i][1], b0, c, 0, 0, 0);
                c = __builtin_amdgcn_mfma_f32_16x16x32_f16(afr[i][0], b1, c, 0, 0, 0);
                acc[i][j] = c;
            }
        }
        asm volatile("s_waitcnt vmcnt(0)" ::: "memory");
        __syncthreads();
    }

    // epilogue: raw softmax stats (logits bounded ~|8| -> no max shift),
    // DPP row_shl reductions across the 16 c16 lanes (zero LDS-port traffic).
    const int wn0 = n0 + brow0;
    float bov[4];
    #pragma unroll
    for (int j = 0; j < 4; ++j) bov[j] = bo[wn0 + j * 16 + c16];
    #pragma unroll
    for (int i = 0; i < 4; ++i) {
        #pragma unroll
        for (int reg = 0; reg < 4; ++reg) {
            float l0 = acc[i][0][reg] + bov[0];
            float l1 = acc[i][1][reg] + bov[1];
            float l2 = acc[i][2][reg] + bov[2];
            float l3 = acc[i][3][reg] + bov[3];
            float m = l0; int a = wn0 + c16;
            if (l1 > m) { m = l1; a = wn0 + 16 + c16; }
            if (l2 > m) { m = l2; a = wn0 + 32 + c16; }
            if (l3 > m) { m = l3; a = wn0 + 48 + c16; }
            float e0 = __expf(l0), e1 = __expf(l1), e2 = __expf(l2), e3 = __expf(l3);
            float s = (e0 + e1) + (e2 + e3);
            float q = fmaf(l0, e0, fmaf(l1, e1, fmaf(l2, e2, l3 * e3)));
            s += dppf<0x108>(s); s += dppf<0x104>(s);
            s += dppf<0x102>(s); s += dppf<0x101>(s);
            q += dppf<0x108>(q); q += dppf<0x104>(q);
            q += dppf<0x102>(q); q += dppf<0x101>(q);
            #define MMERGE(C) { float m2 = dppf<C>(m); int a2 = dppi<C>(a); \
                bool bt = (m2 > m) || (m2 == m && a2 < a); \
                m = bt ? m2 : m; a = bt ? a2 : a; }
            MMERGE(0x108) MMERGE(0x104) MMERGE(0x102) MMERGE(0x101)
            #undef MMERGE
            if (c16 == 0) {
                int grow = m0 + arow0 + (i << 4) + (rg << 2) + reg;
                pstats[(size_t)((blockIdx.x << 1) + (w & 1)) * 8192 + grow] =
                    make_float4(m, s, q, __int_as_float(a));
            }
        }
    }
}

// ---------------- finalize: plain-add merge of 64 panels, outputs -----------
__global__ __launch_bounds__(64) void finalize_kernel(
    const float4* __restrict__ pstats, int* __restrict__ syms,
    float* __restrict__ out_seq, float* __restrict__ out_sel,
    float* __restrict__ out_ent, float* __restrict__ out_ml, int t, int last)
{
    const int row = blockIdx.x * 64 + threadIdx.x;
    float M = -INFINITY, S = 0.f, Q = 0.f; int A = 0;
    #pragma unroll 8
    for (int p = 0; p < 64; ++p) {
        float4 pp = pstats[(size_t)p * 8192 + row];
        S += pp.y; Q += pp.z;
        int a2 = __float_as_int(pp.w);
        if (pp.x > M || (pp.x == M && a2 < A)) { M = pp.x; A = a2; }
    }
    float lse = logf(S);
    float sel = M - lse;
    float ent = lse - Q / S;
    out_seq[(size_t)row * 6 + t] = (float)A;
    out_sel[(size_t)row * 6 + t] = sel;
    float ea = (t == 0) ? ent : (out_ent[row] + ent);
    out_ent[row] = last ? ea * (1.0f / 6.0f) : ea;
    if (t == 0) out_ml[row] = 6.0f;
    syms[row] = A;
}

// ---------------------------------------------------------------------------
extern "C" void kernel_launch(void* const* d_in, const int* in_sizes, int n_in,
                              void* d_out, int out_size, void* d_ws, size_t ws_size,
                              hipStream_t stream) {
    const float* vis  = (const float*)d_in[0];
    const float* Wv   = (const float*)d_in[1];
    const float* bv   = (const float*)d_in[2];
    const float* gk   = (const float*)d_in[3];
    const float* grk  = (const float*)d_in[4];
    const float* bin  = (const float*)d_in[5];
    const float* brec = (const float*)d_in[6];
    const float* Wo   = (const float*)d_in[7];
    const float* bo   = (const float*)d_in[8];
    const float* emb  = (const float*)d_in[9];

    float* out = (float*)d_out;
    float* out_seq = out;                 // (8192, 6)
    float* out_sel = out + 49152;         // (8192, 6)
    float* out_ent = out + 98304;         // (8192,)
    float* out_ml  = out + 106496;        // (8192,)
    float* out_ht  = out + 114688;        // (8192, 256)

    char* ws = (char*)d_ws;
    float*          ph     = (float*)(ws);                       // 8 MB
    float*          hm     = (float*)(ws + 8388608);             // 24 MB
    unsigned short* vis0   = (unsigned short*)(ws + 8388608);    // 8 MB (overlay hm; dead before K2)
    unsigned short* vis1   = (unsigned short*)(ws + 16777216);   // 8 MB (overlay hm)
    unsigned short* h0     = (unsigned short*)(ws + 33554432);   // 4 MB
    unsigned short* h1     = (unsigned short*)(ws + 37748736);   // 4 MB
    unsigned short* w0     = (unsigned short*)(ws + 41943040);   // 2 MB
    unsigned short* w1     = (unsigned short*)(ws + 44040192);   // 2 MB
    float4*         pstats = (float4*)(ws + 46137344);           // 8 MB
    unsigned short* ph0    = (unsigned short*)(ws + 46137344);   // 4 MB (overlay pstats; dead before logits)
    unsigned short* ph1    = (unsigned short*)(ws + 50331648);   // 4 MB (overlay pstats)
    int*            syms   = (int*)(ws + 54525952);              // 32 KB
    unsigned short* wv0    = (unsigned short*)(ws + 54558720);   // 256 KB
    unsigned short* wv1    = (unsigned short*)(ws + 54820864);   // 256 KB
    unsigned short* g0     = (unsigned short*)(ws + 55083008);   // 384 KB
    unsigned short* g1     = (unsigned short*)(ws + 55476224);   // 384 KB

    // one-time weight preps (loop-invariant)
    trans_split<<<dim3(64, 4), 256, 0, stream>>>(Wo, w0, w1, 4096, 256);
    trans_split<<<dim3(4, 8), 256, 0, stream>>>(Wv, wv0, wv1, 256, 512);
    trans_split<<<dim3(12, 4), 256, 0, stream>>>(grk, g0, g1, 768, 256);
    split_ew<<<4096, 256, 0, stream>>>(vis, vis0, vis1, 1048576);

    // K1: prev_hidden = vis @ Wv + bv
    mfma_gemm<512><<<dim3(4, 128), 256, 0, stream>>>(vis0, vis1, wv0, wv1, bv, ph, 256);
    split_ew<<<2048, 256, 0, stream>>>(ph, ph0, ph1, 524288);
    // K2: hm = prev_hidden @ grk + brec (loop-invariant)
    mfma_gemm<256><<<dim3(12, 128), 256, 0, stream>>>(ph0, ph1, g0, g1, brec, hm, 768);

    for (int t = 0; t < 6; ++t) {
        gru_kernel<<<1024, 256, 0, stream>>>(syms, emb, gk, bin, hm, ph,
                                             h0, h1,
                                             (t == 5) ? out_ht : nullptr,
                                             (t > 0) ? 1 : 0);
        logits_mfma<<<dim3(32, 64), 256, 0, stream>>>(h0, h1, w0, w1, bo, pstats);
        finalize_kernel<<<128, 64, 0, stream>>>(pstats, syms, out_seq, out_sel,
                                                out_ent, out_ml, t, (t == 5) ? 1 : 0);
    }
}